// Round 8
// baseline (259.102 us; speedup 1.0000x reference)
//
#include <hip/hip_runtime.h>

// B=8, L=1024, H=1024, NH=16, HD=64. fp32 I/O, bf16 MFMA internals.
// Pipeline: cvt3     : x,w_qkv,w_out fp32 -> bf16                  (~13 us)
//           gemm8p<0>: qk = x@w_qkv^T cols<2048; V scatters to Vt  (51.5 GF)
//           attn     : no-max softmax flash attn, S^T trick        (34.4 GF)
//           gemm8p<1>: out = O@w_out^T + b_out (fp32 out)          (17.2 GF)
// R18: R12's m201-style 8-phase gemm RETRIED with the spill fixed.
// R12 post-mortem: VGPR_Count=128 vs ~215 live (acc[8][4]=128 + af 32 +
// bf 32 + addr) -> compiler spilled acc to scratch (WRITE_SIZE +22MB
// anomaly, 83.6us). Cause: __launch_bounds__(512,2) let the allocator
// target a 128-reg budget although LDS(128KB) already forces 1 block/CU.
// Fix: __launch_bounds__(512,1) -> cap 512, allocator uses ~220, HW still
// 2 waves/SIMD. Schedule/addressing identical to R12 (validated correct).
// attn = R17 (XCD de-interleave, 8 blocks/CU; best measured). cvt3 as ever.

typedef short s16x8 __attribute__((ext_vector_type(8)));
typedef float f32x4 __attribute__((ext_vector_type(4)));
typedef unsigned int u32x2 __attribute__((ext_vector_type(2)));
typedef unsigned int u32x4 __attribute__((ext_vector_type(4)));

__device__ __forceinline__ unsigned short f2bf(float f) {   // RNE
    union { float f; unsigned u; } c; c.f = f;
    return (unsigned short)((c.u + 0x7FFFu + ((c.u >> 16) & 1u)) >> 16);
}
// pack 2 floats -> 2 bf16 (round-half-up) in 3 VALU ops via v_perm
__device__ __forceinline__ unsigned pack2bf(float a, float b) {
    union { float f; unsigned u; } ca, cb; ca.f = a; cb.f = b;
    return __builtin_amdgcn_perm(cb.u + 0x8000u, ca.u + 0x8000u, 0x07060302u);
}

#define GLOAD_LDS(g, l) __builtin_amdgcn_global_load_lds( \
    (const __attribute__((address_space(1))) void*)(g),   \
    (__attribute__((address_space(3))) void*)(l), 16, 0, 0)

// ---------------------------------------------------------------------------
// fp32 -> bf16 convert for the three input tensors.
// ---------------------------------------------------------------------------
__global__ __launch_bounds__(256) void cvt3(
    const float* __restrict__ s0, unsigned short* __restrict__ d0, int n0,
    const float* __restrict__ s1, unsigned short* __restrict__ d1, int n1,
    const float* __restrict__ s2, unsigned short* __restrict__ d2, int n2)
{
    long i = ((long)blockIdx.x * 256 + threadIdx.x) * 8;
    const float* s; unsigned short* d; long off;
    if (i < n0)                  { s = s0; d = d0; off = i; }
    else if (i < (long)n0 + n1)  { s = s1; d = d1; off = i - n0; }
    else                         { s = s2; d = d2; off = i - n0 - n1; }
    f32x4 a = *(const f32x4*)(s + off);
    f32x4 b = *(const f32x4*)(s + off + 4);
    u32x4 r;
    r[0] = pack2bf(a[0], a[1]); r[1] = pack2bf(a[2], a[3]);
    r[2] = pack2bf(b[0], b[1]); r[3] = pack2bf(b[2], b[3]);
    *(u32x4*)(d + off) = r;
}

// ---------------------------------------------------------------------------
// 8-phase GEMM: C[M,N] = A[M,K]*B[N,K]^T, bf16 in, fp32 accum. K = 1024.
// BM=BN=256, BK=64, 512 thr, 8 waves 2M x 4N, per-wave 128x64, acc[8][4].
// LDS 128 KB = 2 K-tile double buffer. Per K-tile 4 phases = C-quadrants
// (0,0)->(0,1)->(1,1)->(1,0), register retention (reads 12/4/8/0).
// Dead-region staging: ph1 (t+1).Ahi, ph2 (t+2).Alo, ph3 (t+2).Blo,
// ph4 (t+2).Bhi; gate vmcnt(6) once per tile (3 newest halves in flight).
// LDS rows of 64 bf16 = 8 x 16B chunks; chunk q of row r at physical
// q ^ (r&7). Pre-swizzled GLOBAL source + linear LDS dest.
// EPI=0: cols<1024 (Q) -> Cq bf16 scaled 0.125*log2(e); 1024..2047 (K) ->
//        Cq unscaled; >=2048 (V) packed-scatter Cv = Vt[(b*16+h)*64+d][l].
// EPI=1: Cf fp32 + bias.
// ---------------------------------------------------------------------------
template<int EPI>
__global__ __launch_bounds__(512, 1) void gemm8p(
    const unsigned short* __restrict__ A, const unsigned short* __restrict__ Bm,
    unsigned short* __restrict__ Cq, unsigned short* __restrict__ Cv,
    float* __restrict__ Cf, const float* __restrict__ bias, int Nout)
{
    __shared__ unsigned short As[2 * 256 * 64];   // 64 KB
    __shared__ unsigned short Bs[2 * 256 * 64];   // 64 KB
    const int tid = threadIdx.x, lane = tid & 63, wave = tid >> 6;
    const int quad = lane >> 4, l16 = lane & 15;
    const int wm = wave >> 2;                     // 2 waves in M
    const int wn = wave & 3;                      // 4 waves in N

    const int gx = gridDim.x, nwg = gx * gridDim.y;
    int wg = blockIdx.y * gx + blockIdx.x;
    wg = (wg & 7) * (nwg >> 3) + (wg >> 3);       // XCD-contiguous (nwg % 8 == 0)
    const int n0 = (wg % gx) * 256, m0 = (wg / gx) * 256;

    const int prow = tid >> 3;
    const int qch  = (tid & 7) ^ (prow & 7);
    const unsigned short* baseA = A  + (size_t)(m0 + prow) * 1024 + qch * 8;
    const unsigned short* baseB = Bm + (size_t)(n0 + prow) * 1024 + qch * 8;
    unsigned short* dA = As + tid * 8;            // wave-linear: base + lane*16B
    unsigned short* dB = Bs + tid * 8;

    auto STGA = [&](int t, int h, int c) {
        GLOAD_LDS(baseA + (h * 128 + c * 64) * 1024 + t * 64,
                  dA + (t & 1) * 16384 + h * 8192 + c * 4096);
    };
    auto STGB = [&](int t, int h, int c) {
        GLOAD_LDS(baseB + (h * 128 + c * 64) * 1024 + t * 64,
                  dB + (t & 1) * 16384 + h * 8192 + c * 4096);
    };

    // prologue: t0 fully + t1 all but Ahi (t1.Ahi comes at t0.ph1)
    STGA(0, 0, 0); STGA(0, 0, 1);   // t0.Alo
    STGB(0, 0, 0); STGB(0, 0, 1);   // t0.Blo
    STGB(0, 1, 0); STGB(0, 1, 1);   // t0.Bhi
    STGA(0, 1, 0); STGA(0, 1, 1);   // t0.Ahi
    STGA(1, 0, 0); STGA(1, 0, 1);   // t1.Alo
    STGB(1, 0, 0); STGB(1, 0, 1);   // t1.Blo
    STGB(1, 1, 0); STGB(1, 1, 1);   // t1.Bhi
    asm volatile("s_waitcnt vmcnt(6)" ::: "memory");   // t0 landed
    __builtin_amdgcn_s_barrier();

    f32x4 acc[8][4] = {};
    s16x8 af[4][2];       // current m-half frags (mh toggles ph2->ph3)
    s16x8 bf[2][2][2];    // [nh][nf][kk], both n-halves retained
    const int sw = l16 & 7;   // frag-read swizzle (row&7 == l16&7)

    auto LDA = [&](int P, int mh) {
        #pragma unroll
        for (int mf = 0; mf < 4; ++mf)
            #pragma unroll
            for (int kk = 0; kk < 2; ++kk)
                af[mf][kk] = *(const s16x8*)(As + P * 16384 +
                    (mh * 128 + wm * 64 + mf * 16 + l16) * 64 +
                    ((kk * 4 + quad) ^ sw) * 8);
    };
    auto LDB = [&](int P, int nh) {
        #pragma unroll
        for (int nf = 0; nf < 2; ++nf)
            #pragma unroll
            for (int kk = 0; kk < 2; ++kk)
                bf[nh][nf][kk] = *(const s16x8*)(Bs + P * 16384 +
                    (wn * 64 + (nh * 2 + nf) * 16 + l16) * 64 +
                    ((kk * 4 + quad) ^ sw) * 8);
    };
    auto MM = [&](int mh, int nh) {
        __builtin_amdgcn_s_setprio(1);
        #pragma unroll
        for (int mf = 0; mf < 4; ++mf)
            #pragma unroll
            for (int nf = 0; nf < 2; ++nf)
                #pragma unroll
                for (int kk = 0; kk < 2; ++kk)
                    acc[mh * 4 + mf][nh * 2 + nf] =
                        __builtin_amdgcn_mfma_f32_16x16x32_bf16(
                            af[mf][kk], bf[nh][nf][kk],
                            acc[mh * 4 + mf][nh * 2 + nf], 0, 0, 0);
        __builtin_amdgcn_s_setprio(0);
    };

    // one K-tile = 4 phases; smode 2 = full staging, 1 = only (t+1).Ahi, 0 = none
    auto TILE = [&](int t, int smode) {
        const int P = t & 1;
        LDA(P, 0); LDB(P, 0);                                   // 12 reads
        if (smode >= 1) { STGA(t + 1, 1, 0); STGA(t + 1, 1, 1); }
        __builtin_amdgcn_s_barrier();
        MM(0, 0);
        __builtin_amdgcn_s_barrier();
        LDB(P, 1);                                              // 4 reads
        if (smode == 2) { STGA(t + 2, 0, 0); STGA(t + 2, 0, 1); }
        __builtin_amdgcn_s_barrier();
        MM(0, 1);
        __builtin_amdgcn_s_barrier();
        LDA(P, 1);                                              // 8 reads
        if (smode == 2) { STGB(t + 2, 0, 0); STGB(t + 2, 0, 1); }
        __builtin_amdgcn_s_barrier();
        MM(1, 1);
        __builtin_amdgcn_s_barrier();
        if (smode == 2) { STGB(t + 2, 1, 0); STGB(t + 2, 1, 1); }
        __builtin_amdgcn_s_barrier();
        MM(1, 0);                                               // 0 reads
        if (smode == 2)      asm volatile("s_waitcnt vmcnt(6)" ::: "memory");
        else if (smode == 1) asm volatile("s_waitcnt vmcnt(0)" ::: "memory");
        __builtin_amdgcn_s_barrier();
    };

    for (int t2 = 0; t2 < 7; ++t2) {    // tiles 0..13: full staging
        TILE(2 * t2,     2);
        TILE(2 * t2 + 1, 2);
    }
    TILE(14, 1);                        // stages only t15.Ahi, gate vmcnt(0)
    TILE(15, 0);                        // no staging, no gate

    // epilogue: C/D layout col=lane&15, row=quad*4+reg
    // row(mi) = m0 + (mi>>2)*128 + wm*64 + (mi&3)*16 + quad*4 + r
    // col(nj) = n0 + wn*64 + nj*16 + l16
    if (EPI == 1) {
        #pragma unroll
        for (int nj = 0; nj < 4; ++nj) {
            int col = n0 + wn * 64 + nj * 16 + l16;
            float bv = bias[col];
            #pragma unroll
            for (int mi = 0; mi < 8; ++mi) {
                int row = m0 + (mi >> 2) * 128 + wm * 64 + (mi & 3) * 16 + quad * 4;
                #pragma unroll
                for (int r = 0; r < 4; ++r)
                    Cf[(size_t)(row + r) * Nout + col] = acc[mi][nj][r] + bv;
            }
        }
    } else if (n0 < 2048) {
        // Q region: prefold softmax scale (1/8) and log2(e) for native exp2
        const float qs = (n0 < 1024) ? 0.18033688f : 1.0f;   // 0.125*log2(e)
        #pragma unroll
        for (int nj = 0; nj < 4; ++nj) {
            int col = n0 + wn * 64 + nj * 16 + l16;
            #pragma unroll
            for (int mi = 0; mi < 8; ++mi) {
                int row = m0 + (mi >> 2) * 128 + wm * 64 + (mi & 3) * 16 + quad * 4;
                #pragma unroll
                for (int r = 0; r < 4; ++r)
                    Cq[(size_t)(row + r) * 2048 + col] = f2bf(acc[mi][nj][r] * qs);
            }
        }
    } else {
        // V region: lane's r=0..3 are 4 consecutive l -> one 8B packed store
        #pragma unroll
        for (int nj = 0; nj < 4; ++nj) {
            int dcol = n0 + wn * 64 + nj * 16 + l16 - 2048;
            int hh = dcol >> 6, dd = dcol & 63;
            #pragma unroll
            for (int mi = 0; mi < 8; ++mi) {
                int row = m0 + (mi >> 2) * 128 + wm * 64 + (mi & 3) * 16 + quad * 4;
                int bb = row >> 10, l = row & 1023;
                u32x2 pw;
                pw[0] = pack2bf(acc[mi][nj][0], acc[mi][nj][1]);
                pw[1] = pack2bf(acc[mi][nj][2], acc[mi][nj][3]);
                *(u32x2*)(Cv + (size_t)((bb * 16 + hh) * 64 + dd) * 1024 + l) = pw;
            }
        }
    }
}

// ---------------------------------------------------------------------------
// Flash attention, no-max softmax (Q pre-scaled by 0.125*log2e -> bare exp2),
// S^T trick with kv-permuted K staging so P's packed C-layout registers are
// directly the PV A-fragments (no P LDS round-trip).
// K staging permutation: LDS row rho = 16t+4u+r holds kv = 32(t>>1)+8u+4(t&1)+r.
// 64 q-rows/block, 2048 blocks = 8 blocks/CU = 32 waves/CU. LDS 16.4 KB.
// R17 XCD de-interleave: swz=(lin&7)*256+(lin>>3), qt=swz&15, bh=swz>>4
// puts all 16 q-tiles of a bh on one XCD. MFMA clusters setprio(1)-wrapped.
// ---------------------------------------------------------------------------
__global__ __launch_bounds__(256) void attn(
    const unsigned short* __restrict__ qk, const unsigned short* __restrict__ Vt,
    unsigned short* __restrict__ O)
{
    __shared__ unsigned short Ks[64 * 64];   // [rho][d] kv-permuted, swizzled
    __shared__ unsigned short Vs[64 * 64];   // [d][kv]  natural, swizzled

    const int lin = blockIdx.y * 16 + blockIdx.x;
    const int swz = (lin & 7) * 256 + (lin >> 3);
    const int qt = swz & 15, bh = swz >> 4;
    const int b = bh >> 4, hh = bh & 15;
    const int q0 = qt * 64;
    const int tid = threadIdx.x, lane = tid & 63, wave = tid >> 6;
    const int quad = lane >> 4, l16 = lane & 15;

    // Q frags direct from global: B-operand, n=q=wave*16+l16, k=s*32+quad*8
    const unsigned short* qrow =
        qk + (size_t)(b * 1024 + q0 + wave * 16 + l16) * 2048 + hh * 64;
    s16x8 qf[2];
    qf[0] = *(const s16x8*)(qrow + quad * 8);
    qf[1] = *(const s16x8*)(qrow + 32 + quad * 8);

    // Staging: wave covers LDS rows rho0 = wave*16+rl and rho1 = rho0+8
    // (rl = lane>>3); chunk swizzle qc = (lane&7) ^ (rho&7), rho&7 == rl.
    // K source rows are the PERMUTED kv for each rho (t = wave for both).
    const int rl = lane >> 3;
    const int qc = (lane & 7) ^ rl;
    const int u0 = rl >> 2, r0 = rl & 3;
    const int kvbase = 32 * (wave >> 1) + 4 * (wave & 1) + r0;
    const int kv0 = kvbase + 8 * u0;          // for LDS row wave*16 + rl
    const int kv1 = kvbase + 8 * (2 + u0);    // for LDS row wave*16 + 8 + rl
    const unsigned short* srcK0 = qk + (size_t)(b * 1024 + kv0) * 2048 + 1024 + hh * 64 + qc * 8;
    const unsigned short* srcK1 = qk + (size_t)(b * 1024 + kv1) * 2048 + 1024 + hh * 64 + qc * 8;
    const unsigned short* srcV0 = Vt + (size_t)(bh * 64 + wave * 16 + rl) * 1024 + qc * 8;
    const unsigned short* srcV1 = Vt + (size_t)(bh * 64 + wave * 16 + 8 + rl) * 1024 + qc * 8;
    unsigned short* dK0 = Ks + (wave * 16 + rl) * 64 + (lane & 7) * 8;
    unsigned short* dK1 = Ks + (wave * 16 + 8 + rl) * 64 + (lane & 7) * 8;
    unsigned short* dV0 = Vs + (wave * 16 + rl) * 64 + (lane & 7) * 8;
    unsigned short* dV1 = Vs + (wave * 16 + 8 + rl) * 64 + (lane & 7) * 8;

    const int sw = l16 & 7;   // frag-read swizzle

    f32x4 Oacc[4] = {};
    float lsum = 0.0f;

    for (int kv = 0; kv < 1024; kv += 64) {
        __syncthreads();
        GLOAD_LDS(srcK0, dK0);
        GLOAD_LDS(srcK1, dK1);
        GLOAD_LDS(srcV0, dV0);
        GLOAD_LDS(srcV1, dV1);
        srcK0 += (size_t)64 * 2048; srcK1 += (size_t)64 * 2048;
        srcV0 += 64; srcV1 += 64;
        __syncthreads();   // vmcnt(0) drain -> K,V in LDS

        // S^T = K Q^T : tile t rows = permuted kv, col q = l16
        f32x4 Sacc[4] = {};
        __builtin_amdgcn_s_setprio(1);
        #pragma unroll
        for (int t = 0; t < 4; ++t) {
            #pragma unroll
            for (int s = 0; s < 2; ++s) {
                s16x8 kf = *(const s16x8*)(Ks + (t * 16 + l16) * 64 + ((s * 4 + quad) ^ sw) * 8);
                Sacc[t] = __builtin_amdgcn_mfma_f32_16x16x32_bf16(kf, qf[s], Sacc[t], 0, 0, 0);
            }
        }
        __builtin_amdgcn_s_setprio(0);
        // p = 2^s; per-lane row-sum; pack pairs (these ARE the PV A-frags)
        unsigned upw[4][2];
        #pragma unroll
        for (int t = 0; t < 4; ++t) {
            float p0 = __builtin_amdgcn_exp2f(Sacc[t][0]);
            float p1 = __builtin_amdgcn_exp2f(Sacc[t][1]);
            float p2 = __builtin_amdgcn_exp2f(Sacc[t][2]);
            float p3 = __builtin_amdgcn_exp2f(Sacc[t][3]);
            lsum += (p0 + p1) + (p2 + p3);
            upw[t][0] = pack2bf(p0, p1);
            upw[t][1] = pack2bf(p2, p3);
        }
        // O += P V^T : A = packed P (register), B = Vs[n=d] (natural)
        __builtin_amdgcn_s_setprio(1);
        #pragma unroll
        for (int s = 0; s < 2; ++s) {
            u32x4 aw;
            aw[0] = upw[2 * s][0];     aw[1] = upw[2 * s][1];
            aw[2] = upw[2 * s + 1][0]; aw[3] = upw[2 * s + 1][1];
            s16x8 pf;
            __builtin_memcpy(&pf, &aw, 16);
            #pragma unroll
            for (int jd = 0; jd < 4; ++jd) {
                s16x8 vf = *(const s16x8*)(Vs + (jd * 16 + l16) * 64 + ((s * 4 + quad) ^ sw) * 8);
                Oacc[jd] = __builtin_amdgcn_mfma_f32_16x16x32_bf16(pf, vf, Oacc[jd], 0, 0, 0);
            }
        }
        __builtin_amdgcn_s_setprio(0);
    }

    // row-sum reduce + write (sum over quads is permutation-invariant)
    lsum += __shfl_xor(lsum, 16, 64);
    lsum += __shfl_xor(lsum, 32, 64);
    float rinv[4];
    #pragma unroll
    for (int r = 0; r < 4; ++r)
        rinv[r] = 1.0f / __shfl(lsum, quad * 4 + r, 64);
    #pragma unroll
    for (int j = 0; j < 4; ++j)
        #pragma unroll
        for (int r = 0; r < 4; ++r) {
            int row = q0 + wave * 16 + quad * 4 + r;
            int col = hh * 64 + j * 16 + l16;
            O[(size_t)(b * 1024 + row) * 1024 + col] = f2bf(Oacc[j][r] * rinv[r]);
        }
}

extern "C" void kernel_launch(void* const* d_in, const int* in_sizes, int n_in,
                              void* d_out, int out_size, void* d_ws, size_t ws_size,
                              hipStream_t stream) {
    const float* x     = (const float*)d_in[0];   // [8192,1024]
    const float* w_qkv = (const float*)d_in[1];   // [3072,1024]
    const float* w_out = (const float*)d_in[2];   // [1024,1024]
    const float* b_out = (const float*)d_in[3];   // [1024]
    float* out = (float*)d_out;                   // [8192,1024] fp32

    const int nx = 8192 * 1024, nwq = 3072 * 1024, nwo = 1024 * 1024;
    unsigned short* xb  = (unsigned short*)d_ws;          // 16.8 MB (dead after gemm1)
    unsigned short* wqb = xb + nx;                        //  6.3 MB
    unsigned short* wob = wqb + nwq;                      //  2.1 MB
    unsigned short* qkb = wob + nwo;                      // [8192,2048] Q|K, 33.6 MB
    unsigned short* Vt  = qkb + (size_t)8192 * 2048;      // [128*64,1024], 16.8 MB
    unsigned short* Ob  = xb;                             // alias: xb dead after gemm1

    cvt3<<<6144, dim3(256), 0, stream>>>(x, xb, nx, w_qkv, wqb, nwq, w_out, wob, nwo);
    gemm8p<0><<<dim3(12, 32), dim3(512), 0, stream>>>(xb, wqb, qkb, Vt, nullptr, nullptr, 3072);
    attn<<<dim3(16, 128), dim3(256), 0, stream>>>(qkb, Vt, Ob);
    gemm8p<1><<<dim3(4, 32), dim3(512), 0, stream>>>(Ob, wob, nullptr, nullptr, out, b_out, 1024);
}

// Round 9
// 230.939 us; speedup vs baseline: 1.1219x; 1.1219x over previous
//
#include <hip/hip_runtime.h>

// B=8, L=1024, H=1024, NH=16, HD=64. fp32 I/O, bf16 MFMA internals.
// Pipeline: cvt3     : x,w_qkv,w_out fp32 -> bf16                  (~13 us)
//           gemm16<0>: qk = x@w_qkv^T cols<2048; V scatters to Vt  (51.5 GF)
//           attn     : no-max softmax flash attn, S^T trick        (34.4 GF)
//           gemm16<1>: out = O@w_out^T + b_out (fp32 out)          (17.2 GF)
// R19 = R17 (best, 226.9us) + XCD by-grouping for gemm16<1> ONLY.
// Accounting across R7/R18 leaves ~65us unexplained; the only unobserved
// kernel is gemm16<1> (always just under the top-5 cutoff). Its grid (8,64)
// gives XCD = lin%8 = bx: each XCD owns ONE B-panel and streams ALL of A
// (16.8MB) through its private L2 -> ~135MB L2-miss at ~2.3TB/s fabric
// ~ 60us (same disease as attn pre-R17, FETCH 142MB). Fix: for EPI==1,
// v=(lin&7)*64+(lin>>3), by=v/8, bx=v%8 -> XCD x owns by in [8x,8x+8):
// per-XCD set = A-slice 2.1MB + full B 2.1MB = 4.2MB ~ L2; B resident
// across sweeps, each A-panel fetched once (~34MB total misses).
// gemm0 keeps its natural map (bx%8 grouping already holds B at 0.8MB/XCD;
// by-grouping would thrash its 6.3MB B). 8-phase gemm arc (R11/R12/R18):
// abandoned -- 83us vs 67us, not a spill (acc in AGPRs), schedule is slower.
// attn = R17: XCD de-interleave + setprio, 8 blocks/CU (best measured).

typedef short s16x8 __attribute__((ext_vector_type(8)));
typedef float f32x4 __attribute__((ext_vector_type(4)));
typedef unsigned int u32x2 __attribute__((ext_vector_type(2)));
typedef unsigned int u32x4 __attribute__((ext_vector_type(4)));

__device__ __forceinline__ unsigned short f2bf(float f) {   // RNE
    union { float f; unsigned u; } c; c.f = f;
    return (unsigned short)((c.u + 0x7FFFu + ((c.u >> 16) & 1u)) >> 16);
}
// pack 2 floats -> 2 bf16 (round-half-up) in 3 VALU ops via v_perm
__device__ __forceinline__ unsigned pack2bf(float a, float b) {
    union { float f; unsigned u; } ca, cb; ca.f = a; cb.f = b;
    return __builtin_amdgcn_perm(cb.u + 0x8000u, ca.u + 0x8000u, 0x07060302u);
}

#define GLOAD_LDS(g, l) __builtin_amdgcn_global_load_lds( \
    (const __attribute__((address_space(1))) void*)(g),   \
    (__attribute__((address_space(3))) void*)(l), 16, 0, 0)

// ---------------------------------------------------------------------------
// fp32 -> bf16 convert for the three input tensors.
// ---------------------------------------------------------------------------
__global__ __launch_bounds__(256) void cvt3(
    const float* __restrict__ s0, unsigned short* __restrict__ d0, int n0,
    const float* __restrict__ s1, unsigned short* __restrict__ d1, int n1,
    const float* __restrict__ s2, unsigned short* __restrict__ d2, int n2)
{
    long i = ((long)blockIdx.x * 256 + threadIdx.x) * 8;
    const float* s; unsigned short* d; long off;
    if (i < n0)                  { s = s0; d = d0; off = i; }
    else if (i < (long)n0 + n1)  { s = s1; d = d1; off = i - n0; }
    else                         { s = s2; d = d2; off = i - n0 - n1; }
    f32x4 a = *(const f32x4*)(s + off);
    f32x4 b = *(const f32x4*)(s + off + 4);
    u32x4 r;
    r[0] = pack2bf(a[0], a[1]); r[1] = pack2bf(a[2], a[3]);
    r[2] = pack2bf(b[0], b[1]); r[3] = pack2bf(b[2], b[3]);
    *(u32x4*)(d + off) = r;
}

// ---------------------------------------------------------------------------
// GEMM: C[M,N] = A[M,K]*B[N,K]^T, bf16 in, fp32 accum. 128x128 tile, BK=64,
// global_load_lds dwordx4. LDS [128][64] elems, XOR swizzle: logical 16B
// chunk q of row r at physical chunk q ^ (r&7) -> 2-way on banks (free).
// EPI=0: cols<1024 (Q) -> Cq bf16 scaled by 0.125*log2(e) (softmax prefold);
//        cols 1024..2047 (K) -> Cq bf16 unscaled; cols>=2048 (V) packed-
//        scatter to Cv = Vt[(b*16+h)*64+d][l] bf16.
// EPI=1: Cf fp32 + bias; XCD by-grouping (see header).
// ---------------------------------------------------------------------------
template<int EPI>
__global__ __launch_bounds__(256) void gemm16(
    const unsigned short* __restrict__ A, const unsigned short* __restrict__ Bm,
    unsigned short* __restrict__ Cq, unsigned short* __restrict__ Cv,
    float* __restrict__ Cf, const float* __restrict__ bias,
    int N, int K)
{
    __shared__ unsigned short As[128 * 64];
    __shared__ unsigned short Bs[128 * 64];
    const int tid = threadIdx.x, lane = tid & 63, wave = tid >> 6;
    const int quad = lane >> 4, l16 = lane & 15;
    const int wm = (wave >> 1) * 64, wn = (wave & 1) * 64;

    int m0, n0;
    if (EPI == 1) {
        // XCD by-grouping: grid (8,64), nwg=512. XCD = lin%8 (HW round-robin).
        // v = (lin&7)*64 + lin>>3 -> XCD x gets v in [64x,64x+64) = by in
        // [8x,8x+8), all bx. Per-XCD L2 set: A-slice 2.1MB + full B 2.1MB.
        const int lin = blockIdx.y * 8 + blockIdx.x;
        const int v = (lin & 7) * 64 + (lin >> 3);
        m0 = (v >> 3) * 128;
        n0 = (v & 7) * 128;
    } else {
        m0 = blockIdx.y * 128;
        n0 = blockIdx.x * 128;
    }

    const int prow = tid >> 3;
    const int qch  = (tid & 7) ^ (prow & 7);
    const unsigned short* gA[4];
    const unsigned short* gB[4];
    #pragma unroll
    for (int c = 0; c < 4; ++c) {
        gA[c] = A + (size_t)(m0 + c * 32 + prow) * K + qch * 8;
        gB[c] = Bm + (size_t)(n0 + c * 32 + prow) * K + qch * 8;
    }
    const int sw = l16 & 7;   // frag-read swizzle

    f32x4 acc[4][4] = {};
    for (int k0 = 0; k0 < K; k0 += 64) {
        __syncthreads();
        #pragma unroll
        for (int c = 0; c < 4; ++c) {
            GLOAD_LDS(gA[c], As + (c * 256 + tid) * 8);
            GLOAD_LDS(gB[c], Bs + (c * 256 + tid) * 8);
            gA[c] += 64; gB[c] += 64;
        }
        __syncthreads();
        #pragma unroll
        for (int s = 0; s < 2; ++s) {
            s16x8 af[4], bf[4];
            const int pc = ((s * 4 + quad) ^ sw) * 8;
            #pragma unroll
            for (int i = 0; i < 4; ++i)
                af[i] = *(const s16x8*)(As + (wm + i * 16 + l16) * 64 + pc);
            #pragma unroll
            for (int j = 0; j < 4; ++j)
                bf[j] = *(const s16x8*)(Bs + (wn + j * 16 + l16) * 64 + pc);
            #pragma unroll
            for (int i = 0; i < 4; ++i)
                #pragma unroll
                for (int j = 0; j < 4; ++j)
                    acc[i][j] = __builtin_amdgcn_mfma_f32_16x16x32_bf16(af[i], bf[j], acc[i][j], 0, 0, 0);
        }
    }

    // epilogue: C/D layout col=lane&15, row=quad*4+reg
    if (EPI == 1) {
        #pragma unroll
        for (int j = 0; j < 4; ++j) {
            int col = n0 + wn + j * 16 + l16;
            float bv = bias[col];
            #pragma unroll
            for (int i = 0; i < 4; ++i)
                #pragma unroll
                for (int r = 0; r < 4; ++r)
                    Cf[(size_t)(m0 + wm + i * 16 + quad * 4 + r) * N + col] = acc[i][j][r] + bv;
        }
    } else if (n0 < 2048) {
        // Q region: prefold softmax scale (1/8) and log2(e) for native exp2
        const float qs = (n0 < 1024) ? 0.18033688f : 1.0f;   // 0.125*log2(e)
        #pragma unroll
        for (int j = 0; j < 4; ++j) {
            int col = n0 + wn + j * 16 + l16;
            #pragma unroll
            for (int i = 0; i < 4; ++i)
                #pragma unroll
                for (int r = 0; r < 4; ++r)
                    Cq[(size_t)(m0 + wm + i * 16 + quad * 4 + r) * 2048 + col] = f2bf(acc[i][j][r] * qs);
        }
    } else {
        // V region: lane's r=0..3 are 4 consecutive l -> one 8B packed store
        #pragma unroll
        for (int j = 0; j < 4; ++j) {
            int dcol = n0 + wn + j * 16 + l16 - 2048;
            int hh = dcol >> 6, dd = dcol & 63;
            #pragma unroll
            for (int i = 0; i < 4; ++i) {
                int row = m0 + wm + i * 16 + quad * 4;
                int bb = row >> 10, l = row & 1023;
                u32x2 pw;
                pw[0] = pack2bf(acc[i][j][0], acc[i][j][1]);
                pw[1] = pack2bf(acc[i][j][2], acc[i][j][3]);
                *(u32x2*)(Cv + (size_t)((bb * 16 + hh) * 64 + dd) * 1024 + l) = pw;
            }
        }
    }
}

// ---------------------------------------------------------------------------
// Flash attention, no-max softmax (Q pre-scaled by 0.125*log2e -> bare exp2),
// S^T trick with kv-permuted K staging so P's packed C-layout registers are
// directly the PV A-fragments (no P LDS round-trip).
// K staging permutation: LDS row rho = 16t+4u+r holds kv = 32(t>>1)+8u+4(t&1)+r.
// 64 q-rows/block, 2048 blocks = 8 blocks/CU = 32 waves/CU. LDS 16.4 KB.
// R17 XCD de-interleave: swz=(lin&7)*256+(lin>>3), qt=swz&15, bh=swz>>4
// puts all 16 q-tiles of a bh on one XCD. MFMA clusters setprio(1)-wrapped.
// ---------------------------------------------------------------------------
__global__ __launch_bounds__(256) void attn(
    const unsigned short* __restrict__ qk, const unsigned short* __restrict__ Vt,
    unsigned short* __restrict__ O)
{
    __shared__ unsigned short Ks[64 * 64];   // [rho][d] kv-permuted, swizzled
    __shared__ unsigned short Vs[64 * 64];   // [d][kv]  natural, swizzled

    const int lin = blockIdx.y * 16 + blockIdx.x;
    const int swz = (lin & 7) * 256 + (lin >> 3);
    const int qt = swz & 15, bh = swz >> 4;
    const int b = bh >> 4, hh = bh & 15;
    const int q0 = qt * 64;
    const int tid = threadIdx.x, lane = tid & 63, wave = tid >> 6;
    const int quad = lane >> 4, l16 = lane & 15;

    // Q frags direct from global: B-operand, n=q=wave*16+l16, k=s*32+quad*8
    const unsigned short* qrow =
        qk + (size_t)(b * 1024 + q0 + wave * 16 + l16) * 2048 + hh * 64;
    s16x8 qf[2];
    qf[0] = *(const s16x8*)(qrow + quad * 8);
    qf[1] = *(const s16x8*)(qrow + 32 + quad * 8);

    // Staging: wave covers LDS rows rho0 = wave*16+rl and rho1 = rho0+8
    // (rl = lane>>3); chunk swizzle qc = (lane&7) ^ (rho&7), rho&7 == rl.
    // K source rows are the PERMUTED kv for each rho (t = wave for both).
    const int rl = lane >> 3;
    const int qc = (lane & 7) ^ rl;
    const int u0 = rl >> 2, r0 = rl & 3;
    const int kvbase = 32 * (wave >> 1) + 4 * (wave & 1) + r0;
    const int kv0 = kvbase + 8 * u0;          // for LDS row wave*16 + rl
    const int kv1 = kvbase + 8 * (2 + u0);    // for LDS row wave*16 + 8 + rl
    const unsigned short* srcK0 = qk + (size_t)(b * 1024 + kv0) * 2048 + 1024 + hh * 64 + qc * 8;
    const unsigned short* srcK1 = qk + (size_t)(b * 1024 + kv1) * 2048 + 1024 + hh * 64 + qc * 8;
    const unsigned short* srcV0 = Vt + (size_t)(bh * 64 + wave * 16 + rl) * 1024 + qc * 8;
    const unsigned short* srcV1 = Vt + (size_t)(bh * 64 + wave * 16 + 8 + rl) * 1024 + qc * 8;
    unsigned short* dK0 = Ks + (wave * 16 + rl) * 64 + (lane & 7) * 8;
    unsigned short* dK1 = Ks + (wave * 16 + 8 + rl) * 64 + (lane & 7) * 8;
    unsigned short* dV0 = Vs + (wave * 16 + rl) * 64 + (lane & 7) * 8;
    unsigned short* dV1 = Vs + (wave * 16 + 8 + rl) * 64 + (lane & 7) * 8;

    const int sw = l16 & 7;   // frag-read swizzle

    f32x4 Oacc[4] = {};
    float lsum = 0.0f;

    for (int kv = 0; kv < 1024; kv += 64) {
        __syncthreads();
        GLOAD_LDS(srcK0, dK0);
        GLOAD_LDS(srcK1, dK1);
        GLOAD_LDS(srcV0, dV0);
        GLOAD_LDS(srcV1, dV1);
        srcK0 += (size_t)64 * 2048; srcK1 += (size_t)64 * 2048;
        srcV0 += 64; srcV1 += 64;
        __syncthreads();   // vmcnt(0) drain -> K,V in LDS

        // S^T = K Q^T : tile t rows = permuted kv, col q = l16
        f32x4 Sacc[4] = {};
        __builtin_amdgcn_s_setprio(1);
        #pragma unroll
        for (int t = 0; t < 4; ++t) {
            #pragma unroll
            for (int s = 0; s < 2; ++s) {
                s16x8 kf = *(const s16x8*)(Ks + (t * 16 + l16) * 64 + ((s * 4 + quad) ^ sw) * 8);
                Sacc[t] = __builtin_amdgcn_mfma_f32_16x16x32_bf16(kf, qf[s], Sacc[t], 0, 0, 0);
            }
        }
        __builtin_amdgcn_s_setprio(0);
        // p = 2^s; per-lane row-sum; pack pairs (these ARE the PV A-frags)
        unsigned upw[4][2];
        #pragma unroll
        for (int t = 0; t < 4; ++t) {
            float p0 = __builtin_amdgcn_exp2f(Sacc[t][0]);
            float p1 = __builtin_amdgcn_exp2f(Sacc[t][1]);
            float p2 = __builtin_amdgcn_exp2f(Sacc[t][2]);
            float p3 = __builtin_amdgcn_exp2f(Sacc[t][3]);
            lsum += (p0 + p1) + (p2 + p3);
            upw[t][0] = pack2bf(p0, p1);
            upw[t][1] = pack2bf(p2, p3);
        }
        // O += P V^T : A = packed P (register), B = Vs[n=d] (natural)
        __builtin_amdgcn_s_setprio(1);
        #pragma unroll
        for (int s = 0; s < 2; ++s) {
            u32x4 aw;
            aw[0] = upw[2 * s][0];     aw[1] = upw[2 * s][1];
            aw[2] = upw[2 * s + 1][0]; aw[3] = upw[2 * s + 1][1];
            s16x8 pf;
            __builtin_memcpy(&pf, &aw, 16);
            #pragma unroll
            for (int jd = 0; jd < 4; ++jd) {
                s16x8 vf = *(const s16x8*)(Vs + (jd * 16 + l16) * 64 + ((s * 4 + quad) ^ sw) * 8);
                Oacc[jd] = __builtin_amdgcn_mfma_f32_16x16x32_bf16(pf, vf, Oacc[jd], 0, 0, 0);
            }
        }
        __builtin_amdgcn_s_setprio(0);
    }

    // row-sum reduce + write (sum over quads is permutation-invariant)
    lsum += __shfl_xor(lsum, 16, 64);
    lsum += __shfl_xor(lsum, 32, 64);
    float rinv[4];
    #pragma unroll
    for (int r = 0; r < 4; ++r)
        rinv[r] = 1.0f / __shfl(lsum, quad * 4 + r, 64);
    #pragma unroll
    for (int j = 0; j < 4; ++j)
        #pragma unroll
        for (int r = 0; r < 4; ++r) {
            int row = q0 + wave * 16 + quad * 4 + r;
            int col = hh * 64 + j * 16 + l16;
            O[(size_t)(b * 1024 + row) * 1024 + col] = f2bf(Oacc[j][r] * rinv[r]);
        }
}

extern "C" void kernel_launch(void* const* d_in, const int* in_sizes, int n_in,
                              void* d_out, int out_size, void* d_ws, size_t ws_size,
                              hipStream_t stream) {
    const float* x     = (const float*)d_in[0];   // [8192,1024]
    const float* w_qkv = (const float*)d_in[1];   // [3072,1024]
    const float* w_out = (const float*)d_in[2];   // [1024,1024]
    const float* b_out = (const float*)d_in[3];   // [1024]
    float* out = (float*)d_out;                   // [8192,1024] fp32

    const int nx = 8192 * 1024, nwq = 3072 * 1024, nwo = 1024 * 1024;
    unsigned short* xb  = (unsigned short*)d_ws;          // 16.8 MB (dead after gemm1)
    unsigned short* wqb = xb + nx;                        //  6.3 MB
    unsigned short* wob = wqb + nwq;                      //  2.1 MB
    unsigned short* qkb = wob + nwo;                      // [8192,2048] Q|K, 33.6 MB
    unsigned short* Vt  = qkb + (size_t)8192 * 2048;      // [128*64,1024], 16.8 MB
    unsigned short* Ob  = xb;                             // alias: xb dead after gemm1

    dim3 blk(256);
    cvt3<<<6144, blk, 0, stream>>>(x, xb, nx, w_qkv, wqb, nwq, w_out, wob, nwo);
    gemm16<0><<<dim3(24, 64), blk, 0, stream>>>(xb, wqb, qkb, Vt, nullptr, nullptr, 3072, 1024);
    attn<<<dim3(16, 128), blk, 0, stream>>>(qkb, Vt, Ob);
    gemm16<1><<<dim3(8, 64), blk, 0, stream>>>(Ob, wob, nullptr, nullptr, out, b_out, 1024, 1024);
}